// Round 1
// baseline (894.483 us; speedup 1.0000x reference)
//
#include <hip/hip_runtime.h>

#define H 128

// ---------------- CSR build ----------------

__global__ void hist_kernel(const int* __restrict__ ei, int E, int* __restrict__ deg) {
    int e = blockIdx.x * blockDim.x + threadIdx.x;
    if (e < E) atomicAdd(&deg[ei[e]], 1);
}

__global__ void scan_kernel(const int* __restrict__ deg, int* __restrict__ off, int N) {
    __shared__ int sums[1024];
    int t = threadIdx.x;
    int chunk = (N + 1023) >> 10;
    int lo = t * chunk, hi = min(lo + chunk, N);
    int s = 0;
    for (int i = lo; i < hi; ++i) s += deg[i];
    sums[t] = s;
    __syncthreads();
    for (int d = 1; d < 1024; d <<= 1) {
        int v = (t >= d) ? sums[t - d] : 0;
        __syncthreads();
        sums[t] += v;
        __syncthreads();
    }
    int base = (t == 0) ? 0 : sums[t - 1];
    for (int i = lo; i < hi; ++i) { off[i] = base; base += deg[i]; }
    if (t == 1023) off[N] = sums[1023];
}

__global__ void fill_kernel(const int* __restrict__ ei, int E,
                            const int* __restrict__ off, int* __restrict__ cnt2,
                            int* __restrict__ cols_s) {
    int e = blockIdx.x * blockDim.x + threadIdx.x;
    if (e < E) {
        int r = ei[e];
        int pos = off[r] + atomicAdd(&cnt2[r], 1);
        cols_s[pos] = ei[E + e];
    }
}

// c_i[k] = sum_j W3[i][k][j] * relu(W4[i][j])
__global__ void cvec_kernel(const float* __restrict__ W3, const float* __restrict__ W4,
                            float* __restrict__ cvec) {
    int i = blockIdx.x, k = threadIdx.x;
    const float* w3 = W3 + i * H * H + k * H;
    const float* w4 = W4 + i * H;
    float s = 0.f;
    for (int j = 0; j < H; ++j) s += w3[j] * fmaxf(w4[j], 0.f);
    cvec[i * H + k] = s;
}

// ---------------- GEMM: C[n][j] = sum_k A[n][k] * W[j][k]  (+ deg[n]*cvec[j]) (+relu) ----
// Block: 256 thr, tile 128 rows x 128 cols. 4 waves, each wave = 8x8 threads,
// each thread 8x8 outputs. LDS staged in K-chunks of 32, XOR-swizzled float4
// slots (slot = k4 ^ ((row>>3)&7)) -> conflict-free ds_read_b128.

template<int BIAS, int RELU>
__global__ __launch_bounds__(256)
void gemm_xWT(const float* __restrict__ A, const float* __restrict__ W,
              const int* __restrict__ deg, const float* __restrict__ cvec,
              float* __restrict__ C, int N)
{
    __shared__ float4 As4[128 * 8];
    __shared__ float4 Ws4[128 * 8];
    int t = threadIdx.x;
    int wv = t >> 6, l = t & 63;
    int tx = l & 7, ty = l >> 3;              // 8x8 lanes in wave
    int r0 = (wv >> 1) * 64 + ty * 8;         // block-local rows of micro tile
    int c0 = (wv & 1) * 64 + tx * 8;          // block-local cols
    int rowBase = blockIdx.x * 128;

    float acc[8][8];
#pragma unroll
    for (int i = 0; i < 8; ++i)
#pragma unroll
        for (int j = 0; j < 8; ++j) acc[i][j] = 0.f;

    const float4* Ag = (const float4*)A;
    const float4* Wg = (const float4*)W;

    for (int kc = 0; kc < 4; ++kc) {
#pragma unroll
        for (int ps = 0; ps < 4; ++ps) {
            int idx = ps * 256 + t;           // 0..1023
            int r = idx >> 3, k4 = idx & 7;
            int slot = k4 ^ ((r >> 3) & 7);
            float4 v = make_float4(0.f, 0.f, 0.f, 0.f);
            int gr = rowBase + r;
            if (gr < N) v = Ag[gr * 32 + kc * 8 + k4];
            As4[r * 8 + slot] = v;
            Ws4[r * 8 + slot] = Wg[r * 32 + kc * 8 + k4];
        }
        __syncthreads();
#pragma unroll
        for (int k4 = 0; k4 < 8; ++k4) {
            float4 a[8], w[8];
#pragma unroll
            for (int i = 0; i < 8; ++i) a[i] = As4[(r0 + i) * 8 + (k4 ^ ty)];
#pragma unroll
            for (int j = 0; j < 8; ++j) w[j] = Ws4[(c0 + j) * 8 + (k4 ^ tx)];
#pragma unroll
            for (int i = 0; i < 8; ++i)
#pragma unroll
                for (int j = 0; j < 8; ++j) {
                    acc[i][j] += a[i].x * w[j].x;
                    acc[i][j] += a[i].y * w[j].y;
                    acc[i][j] += a[i].z * w[j].z;
                    acc[i][j] += a[i].w * w[j].w;
                }
        }
        __syncthreads();
    }

    float cv[8];
    if (BIAS) {
#pragma unroll
        for (int j = 0; j < 8; ++j) cv[j] = cvec[c0 + j];
    }
#pragma unroll
    for (int i = 0; i < 8; ++i) {
        int gr = rowBase + r0 + i;
        if (gr < N) {
            float d = 0.f;
            if (BIAS) d = (float)deg[gr];
#pragma unroll
            for (int jq = 0; jq < 2; ++jq) {
                float4 o;
                o.x = acc[i][jq * 4 + 0];
                o.y = acc[i][jq * 4 + 1];
                o.z = acc[i][jq * 4 + 2];
                o.w = acc[i][jq * 4 + 3];
                if (BIAS) {
                    o.x += d * cv[jq * 4 + 0];
                    o.y += d * cv[jq * 4 + 1];
                    o.z += d * cv[jq * 4 + 2];
                    o.w += d * cv[jq * 4 + 3];
                }
                if (RELU) {
                    o.x = fmaxf(o.x, 0.f);
                    o.y = fmaxf(o.y, 0.f);
                    o.z = fmaxf(o.z, 0.f);
                    o.w = fmaxf(o.w, 0.f);
                }
                ((float4*)C)[gr * 32 + (c0 >> 2) + jq] = o;
            }
        }
    }
}

// ---------------- aggregation: hb[n] = relu(hb[n] + sum_{e in row n} p[cols[e]]) ----
// one wave per node; lane owns 2 consecutive floats (float2, 512B/wave per edge)

__global__ void aggregate_relu(float* __restrict__ hb, const float* __restrict__ p,
                               const int* __restrict__ off, const int* __restrict__ cols,
                               int N)
{
    int node = blockIdx.x * 4 + (threadIdx.x >> 6);
    if (node >= N) return;
    int l = threadIdx.x & 63;
    int s = off[node], e = off[node + 1];
    const float2* p2 = (const float2*)p;
    float ax = 0.f, ay = 0.f;
    int i = s;
    for (; i + 4 <= e; i += 4) {
        int c0 = cols[i], c1 = cols[i + 1], c2 = cols[i + 2], c3 = cols[i + 3];
        float2 v0 = p2[c0 * 64 + l];
        float2 v1 = p2[c1 * 64 + l];
        float2 v2 = p2[c2 * 64 + l];
        float2 v3 = p2[c3 * 64 + l];
        ax += v0.x + v1.x + v2.x + v3.x;
        ay += v0.y + v1.y + v2.y + v3.y;
    }
    for (; i < e; ++i) {
        int c = cols[i];
        float2 v = p2[c * 64 + l];
        ax += v.x; ay += v.y;
    }
    float2 b = ((const float2*)hb)[node * 64 + l];
    float2 o;
    o.x = fmaxf(b.x + ax, 0.f);
    o.y = fmaxf(b.y + ay, 0.f);
    ((float2*)hb)[node * 64 + l] = o;
}

// ---------------- launch ----------------

extern "C" void kernel_launch(void* const* d_in, const int* in_sizes, int n_in,
                              void* d_out, int out_size, void* d_ws, size_t ws_size,
                              hipStream_t stream)
{
    const float* x  = (const float*)d_in[0];
    const int*   ei = (const int*)d_in[1];
    const float* W1 = (const float*)d_in[2];
    const float* W2 = (const float*)d_in[3];
    const float* W3 = (const float*)d_in[4];
    const float* W4 = (const float*)d_in[5];
    int N   = in_sizes[0] / H;
    int E   = in_sizes[1] / 2;
    int HOP = in_sizes[2] / (H * H);

    char* ws = (char*)d_ws;
    int*   deg   = (int*)ws;                 // N
    int*   off   = deg + N;                  // N+1
    int*   cnt2  = off + N + 1;              // N
    int*   colss = cnt2 + N;                 // E
    float* cvec  = (float*)(colss + E);      // HOP*H
    size_t fo = (((size_t)((char*)(cvec + HOP * H) - ws)) + 255) & ~(size_t)255;
    float* p = (float*)(ws + fo);            // N*H
    float* h = p + (size_t)N * H;            // N*H

    hipMemsetAsync(deg, 0, sizeof(int) * N, stream);
    hipMemsetAsync(cnt2, 0, sizeof(int) * N, stream);
    hist_kernel<<<(E + 255) / 256, 256, 0, stream>>>(ei, E, deg);
    scan_kernel<<<1, 1024, 0, stream>>>(deg, off, N);
    fill_kernel<<<(E + 255) / 256, 256, 0, stream>>>(ei, E, off, cnt2, colss);
    cvec_kernel<<<HOP, H, 0, stream>>>(W3, W4, cvec);

    int gblocks = (N + 127) / 128;
    float* out = (float*)d_out;

    // hop 0: h0 = relu(x@W1[0]^T + deg*c0)   (nbr_agg == 0 since h starts at 0)
    float* h0dst = (HOP == 1) ? out : h;
    gemm_xWT<1, 1><<<gblocks, 256, 0, stream>>>(x, W1, deg, cvec, h0dst, N);

    for (int i = 1; i < HOP; ++i) {
        float* dst = (i == HOP - 1) ? out : h;
        // p = h_{i-1} @ W2[i]^T
        gemm_xWT<0, 0><<<gblocks, 256, 0, stream>>>(h, W2 + (size_t)i * H * H,
                                                    nullptr, nullptr, p, N);
        // dst = x @ W1[i]^T + deg*c_i   (no relu yet)
        gemm_xWT<1, 0><<<gblocks, 256, 0, stream>>>(x, W1 + (size_t)i * H * H,
                                                    deg, cvec + i * H, dst, N);
        // dst = relu(dst + A p)
        aggregate_relu<<<(N + 3) / 4, 256, 0, stream>>>(dst, p, off, colss, N);
    }
}

// Round 2
// 740.236 us; speedup vs baseline: 1.2084x; 1.2084x over previous
//
#include <hip/hip_runtime.h>

#define H 128

// ---------------- CSR build ----------------

__global__ void hist_kernel(const int* __restrict__ ei, int E, int* __restrict__ deg) {
    int e = blockIdx.x * blockDim.x + threadIdx.x;
    if (e < E) atomicAdd(&deg[ei[e]], 1);
}

// ---- two-level scan over deg[N] -> off[N+1] (exclusive) ----
// chunk = 512 elements per block

__global__ void scan_reduce(const int* __restrict__ deg, int* __restrict__ bsum, int N) {
    __shared__ int sm[256];
    int lo = blockIdx.x * 512;
    int t = threadIdx.x;
    int a = (lo + t < N) ? deg[lo + t] : 0;
    int b = (lo + 256 + t < N) ? deg[lo + 256 + t] : 0;
    sm[t] = a + b;
    __syncthreads();
    for (int d = 128; d; d >>= 1) {
        if (t < d) sm[t] += sm[t + d];
        __syncthreads();
    }
    if (t == 0) bsum[blockIdx.x] = sm[0];
}

__global__ void scan_bsums(int* __restrict__ bsum, int* __restrict__ off, int B, int N) {
    __shared__ int s[1024];
    int t = threadIdx.x;
    int v = (t < B) ? bsum[t] : 0;
    s[t] = v;
    __syncthreads();
    for (int d = 1; d < 1024; d <<= 1) {
        int u = (t >= d) ? s[t - d] : 0;
        __syncthreads();
        s[t] += u;
        __syncthreads();
    }
    if (t < B) bsum[t] = s[t] - v;          // exclusive block offset
    if (t == 1023) off[N] = s[1023];        // total
}

__global__ void scan_write(const int* __restrict__ deg, const int* __restrict__ bsum,
                           int* __restrict__ off, int N) {
    __shared__ int sm[256];
    int lo = blockIdx.x * 512;
    int t = threadIdx.x;
    int i0 = lo + 2 * t, i1 = i0 + 1;
    int d0 = (i0 < N) ? deg[i0] : 0;
    int d1 = (i1 < N) ? deg[i1] : 0;
    int p = d0 + d1;
    sm[t] = p;
    __syncthreads();
    for (int d = 1; d < 256; d <<= 1) {
        int u = (t >= d) ? sm[t - d] : 0;
        __syncthreads();
        sm[t] += u;
        __syncthreads();
    }
    int ex = sm[t] - p + bsum[blockIdx.x];
    if (i0 < N) off[i0] = ex;
    if (i1 < N) off[i1] = ex + d0;
}

__global__ void fill_kernel(const int* __restrict__ ei, int E,
                            const int* __restrict__ off, int* __restrict__ cnt2,
                            int* __restrict__ cols_s) {
    int e = blockIdx.x * blockDim.x + threadIdx.x;
    if (e < E) {
        int r = ei[e];
        int pos = off[r] + atomicAdd(&cnt2[r], 1);
        cols_s[pos] = ei[E + e];
    }
}

// c_i[k] = sum_j W3[i][k][j] * relu(W4[i][j])
__global__ void cvec_kernel(const float* __restrict__ W3, const float* __restrict__ W4,
                            float* __restrict__ cvec) {
    int i = blockIdx.x, k = threadIdx.x;
    const float* w3 = W3 + i * H * H + k * H;
    const float* w4 = W4 + i * H;
    float s = 0.f;
    for (int j = 0; j < H; ++j) s += w3[j] * fmaxf(w4[j], 0.f);
    cvec[i * H + k] = s;
}

// ---------------- GEMM: C[n][j] = sum_k A[n][k] * W[j][k]  (+ deg[n]*cvec[j]) (+relu) ----

template<int BIAS, int RELU>
__global__ __launch_bounds__(256)
void gemm_xWT(const float* __restrict__ A, const float* __restrict__ W,
              const int* __restrict__ deg, const float* __restrict__ cvec,
              float* __restrict__ C, int N)
{
    __shared__ float4 As4[128 * 8];
    __shared__ float4 Ws4[128 * 8];
    int t = threadIdx.x;
    int wv = t >> 6, l = t & 63;
    int tx = l & 7, ty = l >> 3;              // 8x8 lanes in wave
    int r0 = (wv >> 1) * 64 + ty * 8;         // block-local rows of micro tile
    int c0 = (wv & 1) * 64 + tx * 8;          // block-local cols
    int rowBase = blockIdx.x * 128;

    float acc[8][8];
#pragma unroll
    for (int i = 0; i < 8; ++i)
#pragma unroll
        for (int j = 0; j < 8; ++j) acc[i][j] = 0.f;

    const float4* Ag = (const float4*)A;
    const float4* Wg = (const float4*)W;

    for (int kc = 0; kc < 4; ++kc) {
#pragma unroll
        for (int ps = 0; ps < 4; ++ps) {
            int idx = ps * 256 + t;           // 0..1023
            int r = idx >> 3, k4 = idx & 7;
            int slot = k4 ^ ((r >> 3) & 7);
            float4 v = make_float4(0.f, 0.f, 0.f, 0.f);
            int gr = rowBase + r;
            if (gr < N) v = Ag[gr * 32 + kc * 8 + k4];
            As4[r * 8 + slot] = v;
            Ws4[r * 8 + slot] = Wg[r * 32 + kc * 8 + k4];
        }
        __syncthreads();
#pragma unroll
        for (int k4 = 0; k4 < 8; ++k4) {
            float4 a[8], w[8];
#pragma unroll
            for (int i = 0; i < 8; ++i) a[i] = As4[(r0 + i) * 8 + (k4 ^ ty)];
#pragma unroll
            for (int j = 0; j < 8; ++j) w[j] = Ws4[(c0 + j) * 8 + (k4 ^ tx)];
#pragma unroll
            for (int i = 0; i < 8; ++i)
#pragma unroll
                for (int j = 0; j < 8; ++j) {
                    acc[i][j] += a[i].x * w[j].x;
                    acc[i][j] += a[i].y * w[j].y;
                    acc[i][j] += a[i].z * w[j].z;
                    acc[i][j] += a[i].w * w[j].w;
                }
        }
        __syncthreads();
    }

    float cv[8];
    if (BIAS) {
#pragma unroll
        for (int j = 0; j < 8; ++j) cv[j] = cvec[c0 + j];
    }
#pragma unroll
    for (int i = 0; i < 8; ++i) {
        int gr = rowBase + r0 + i;
        if (gr < N) {
            float d = 0.f;
            if (BIAS) d = (float)deg[gr];
#pragma unroll
            for (int jq = 0; jq < 2; ++jq) {
                float4 o;
                o.x = acc[i][jq * 4 + 0];
                o.y = acc[i][jq * 4 + 1];
                o.z = acc[i][jq * 4 + 2];
                o.w = acc[i][jq * 4 + 3];
                if (BIAS) {
                    o.x += d * cv[jq * 4 + 0];
                    o.y += d * cv[jq * 4 + 1];
                    o.z += d * cv[jq * 4 + 2];
                    o.w += d * cv[jq * 4 + 3];
                }
                if (RELU) {
                    o.x = fmaxf(o.x, 0.f);
                    o.y = fmaxf(o.y, 0.f);
                    o.z = fmaxf(o.z, 0.f);
                    o.w = fmaxf(o.w, 0.f);
                }
                ((float4*)C)[gr * 32 + (c0 >> 2) + jq] = o;
            }
        }
    }
}

// ---------------- aggregation: hb[n] = relu(hb[n] + sum_{e in row n} p[cols[e]]) ----

__global__ void aggregate_relu(float* __restrict__ hb, const float* __restrict__ p,
                               const int* __restrict__ off, const int* __restrict__ cols,
                               int N)
{
    int node = blockIdx.x * 4 + (threadIdx.x >> 6);
    if (node >= N) return;
    int l = threadIdx.x & 63;
    int s = off[node], e = off[node + 1];
    const float2* p2 = (const float2*)p;
    float ax = 0.f, ay = 0.f;
    int i = s;
    for (; i + 4 <= e; i += 4) {
        int c0 = cols[i], c1 = cols[i + 1], c2 = cols[i + 2], c3 = cols[i + 3];
        float2 v0 = p2[c0 * 64 + l];
        float2 v1 = p2[c1 * 64 + l];
        float2 v2 = p2[c2 * 64 + l];
        float2 v3 = p2[c3 * 64 + l];
        ax += v0.x + v1.x + v2.x + v3.x;
        ay += v0.y + v1.y + v2.y + v3.y;
    }
    for (; i < e; ++i) {
        int c = cols[i];
        float2 v = p2[c * 64 + l];
        ax += v.x; ay += v.y;
    }
    float2 b = ((const float2*)hb)[node * 64 + l];
    float2 o;
    o.x = fmaxf(b.x + ax, 0.f);
    o.y = fmaxf(b.y + ay, 0.f);
    ((float2*)hb)[node * 64 + l] = o;
}

// ---------------- launch ----------------

extern "C" void kernel_launch(void* const* d_in, const int* in_sizes, int n_in,
                              void* d_out, int out_size, void* d_ws, size_t ws_size,
                              hipStream_t stream)
{
    const float* x  = (const float*)d_in[0];
    const int*   ei = (const int*)d_in[1];
    const float* W1 = (const float*)d_in[2];
    const float* W2 = (const float*)d_in[3];
    const float* W3 = (const float*)d_in[4];
    const float* W4 = (const float*)d_in[5];
    int N   = in_sizes[0] / H;
    int E   = in_sizes[1] / 2;
    int HOP = in_sizes[2] / (H * H);

    char* ws = (char*)d_ws;
    int*   deg   = (int*)ws;                 // N
    int*   off   = deg + N;                  // N+1
    int*   cnt2  = off + N + 1;              // N
    int*   colss = cnt2 + N;                 // E
    int*   bsum  = colss + E;                // <=1024
    float* cvec  = (float*)(bsum + 1024);    // HOP*H
    size_t fo = (((size_t)((char*)(cvec + HOP * H) - ws)) + 255) & ~(size_t)255;
    float* p = (float*)(ws + fo);            // N*H
    float* h = p + (size_t)N * H;            // N*H

    hipMemsetAsync(deg, 0, sizeof(int) * N, stream);
    hipMemsetAsync(cnt2, 0, sizeof(int) * N, stream);
    hist_kernel<<<(E + 255) / 256, 256, 0, stream>>>(ei, E, deg);

    int Bq = (N + 511) / 512;                // <= 1024 for N <= 524288
    scan_reduce<<<Bq, 256, 0, stream>>>(deg, bsum, N);
    scan_bsums<<<1, 1024, 0, stream>>>(bsum, off, Bq, N);
    scan_write<<<Bq, 256, 0, stream>>>(deg, bsum, off, N);

    fill_kernel<<<(E + 255) / 256, 256, 0, stream>>>(ei, E, off, cnt2, colss);
    cvec_kernel<<<HOP, H, 0, stream>>>(W3, W4, cvec);

    int gblocks = (N + 127) / 128;
    float* out = (float*)d_out;

    // hop 0: h0 = relu(x@W1[0]^T + deg*c0)   (nbr_agg == 0 since h starts at 0)
    float* h0dst = (HOP == 1) ? out : h;
    gemm_xWT<1, 1><<<gblocks, 256, 0, stream>>>(x, W1, deg, cvec, h0dst, N);

    for (int i = 1; i < HOP; ++i) {
        float* dst = (i == HOP - 1) ? out : h;
        // p = h_{i-1} @ W2[i]^T
        gemm_xWT<0, 0><<<gblocks, 256, 0, stream>>>(h, W2 + (size_t)i * H * H,
                                                    nullptr, nullptr, p, N);
        // dst = x @ W1[i]^T + deg*c_i   (no relu yet)
        gemm_xWT<1, 0><<<gblocks, 256, 0, stream>>>(x, W1 + (size_t)i * H * H,
                                                    deg, cvec + i * H, dst, N);
        // dst = relu(dst + A p)
        aggregate_relu<<<(N + 3) / 4, 256, 0, stream>>>(dst, p, off, colss, N);
    }
}

// Round 3
// 446.188 us; speedup vs baseline: 2.0047x; 1.6590x over previous
//
#include <hip/hip_runtime.h>

#define H 128

typedef __attribute__((ext_vector_type(8))) short bf16x8;
typedef __attribute__((ext_vector_type(4))) float f32x4;
typedef unsigned int uint;
typedef unsigned short ushort;

__device__ __forceinline__ ushort f2bf(float f) {
    uint u = __builtin_bit_cast(uint, f);
    uint r = u + 0x7FFFu + ((u >> 16) & 1u);
    return (ushort)(r >> 16);
}
__device__ __forceinline__ float bf_lo(uint u) {
    return __builtin_bit_cast(float, u << 16);
}
__device__ __forceinline__ float bf_hi(uint u) {
    return __builtin_bit_cast(float, u & 0xFFFF0000u);
}

// ---------------- CSR build ----------------

__global__ void hist_kernel(const int* __restrict__ ei, int E, int* __restrict__ deg) {
    int e = blockIdx.x * blockDim.x + threadIdx.x;
    if (e < E) atomicAdd(&deg[ei[e]], 1);
}

__global__ void scan_reduce(const int* __restrict__ deg, int* __restrict__ bsum, int N) {
    __shared__ int sm[256];
    int lo = blockIdx.x * 512;
    int t = threadIdx.x;
    int a = (lo + t < N) ? deg[lo + t] : 0;
    int b = (lo + 256 + t < N) ? deg[lo + 256 + t] : 0;
    sm[t] = a + b;
    __syncthreads();
    for (int d = 128; d; d >>= 1) {
        if (t < d) sm[t] += sm[t + d];
        __syncthreads();
    }
    if (t == 0) bsum[blockIdx.x] = sm[0];
}

__global__ void scan_bsums(int* __restrict__ bsum, int* __restrict__ off, int B, int N) {
    __shared__ int s[1024];
    int t = threadIdx.x;
    int v = (t < B) ? bsum[t] : 0;
    s[t] = v;
    __syncthreads();
    for (int d = 1; d < 1024; d <<= 1) {
        int u = (t >= d) ? s[t - d] : 0;
        __syncthreads();
        s[t] += u;
        __syncthreads();
    }
    if (t < B) bsum[t] = s[t] - v;          // exclusive block offset
    if (t == 1023) off[N] = s[1023];        // total
}

__global__ void scan_write(const int* __restrict__ deg, const int* __restrict__ bsum,
                           int* __restrict__ off, int N) {
    __shared__ int sm[256];
    int lo = blockIdx.x * 512;
    int t = threadIdx.x;
    int i0 = lo + 2 * t, i1 = i0 + 1;
    int d0 = (i0 < N) ? deg[i0] : 0;
    int d1 = (i1 < N) ? deg[i1] : 0;
    int p = d0 + d1;
    sm[t] = p;
    __syncthreads();
    for (int d = 1; d < 256; d <<= 1) {
        int u = (t >= d) ? sm[t - d] : 0;
        __syncthreads();
        sm[t] += u;
        __syncthreads();
    }
    int ex = sm[t] - p + bsum[blockIdx.x];
    if (i0 < N) off[i0] = ex;
    if (i1 < N) off[i1] = ex + d0;
}

__global__ void fill_kernel(const int* __restrict__ ei, int E,
                            const int* __restrict__ off, int* __restrict__ cnt2,
                            int* __restrict__ cols_s) {
    int e = blockIdx.x * blockDim.x + threadIdx.x;
    if (e < E) {
        int r = ei[e];
        int pos = off[r] + atomicAdd(&cnt2[r], 1);
        cols_s[pos] = ei[E + e];
    }
}

// c_i[k] = sum_j W3[i][k][j] * relu(W4[i][j])
__global__ void cvec_kernel(const float* __restrict__ W3, const float* __restrict__ W4,
                            float* __restrict__ cvec) {
    int i = blockIdx.x, k = threadIdx.x;
    const float* w3 = W3 + i * H * H + k * H;
    const float* w4 = W4 + i * H;
    float s = 0.f;
    for (int j = 0; j < H; ++j) s += w3[j] * fmaxf(w4[j], 0.f);
    cvec[i * H + k] = s;
}

// ---------------- f32 -> bf16 cast (vectorized, 8 elems/thread) ----------------

__global__ void cast_bf16(const float* __restrict__ in, ushort* __restrict__ outp, int n8) {
    int i = blockIdx.x * blockDim.x + threadIdx.x;
    if (i >= n8) return;
    const float4* in4 = (const float4*)in;
    float4 a = in4[2 * i], b = in4[2 * i + 1];
    uint4 o;
    o.x = (uint)f2bf(a.x) | ((uint)f2bf(a.y) << 16);
    o.y = (uint)f2bf(a.z) | ((uint)f2bf(a.w) << 16);
    o.z = (uint)f2bf(b.x) | ((uint)f2bf(b.y) << 16);
    o.w = (uint)f2bf(b.z) | ((uint)f2bf(b.w) << 16);
    ((uint4*)outp)[i] = o;
}

// ---------------- MFMA GEMM: C[n][j] = sum_k A[n][k]*W[j][k] (+deg*cvec) (+relu) ----
// A, W bf16 row-major [*][128]. Block = 256 thr (4 waves), tile 128 rows x 128 cols.
// Wave w: rows w*32..w*32+32 (2 row-tiles of 16), all 128 cols (8 col-tiles).
// LDS: K staged in 2 chunks of 64; 16B slots XOR-swizzled (slot ^ (row&7)) ->
// <=2-way bank conflict on ds_read_b128 (free).

template<int ADD_DEGC, int RELU, int OUT_BF16>
__global__ __launch_bounds__(256)
void gemm_mfma(const ushort* __restrict__ A, const ushort* __restrict__ W,
               const int* __restrict__ deg, const float* __restrict__ cvec,
               void* __restrict__ Cout, int N)
{
    __shared__ uint4 A4[128 * 8];
    __shared__ uint4 W4[128 * 8];
    int t = threadIdx.x;
    int w = t >> 6, l = t & 63;
    int lg = l >> 4, lr = l & 15;
    int rowBase = blockIdx.x * 128;

    f32x4 acc[2][8];
#pragma unroll
    for (int rt = 0; rt < 2; ++rt)
#pragma unroll
        for (int ct = 0; ct < 8; ++ct) acc[rt][ct] = (f32x4){0.f, 0.f, 0.f, 0.f};

    const uint4* Ag = (const uint4*)A;   // 16 uint4 per row
    const uint4* Wg = (const uint4*)W;

    for (int kc = 0; kc < 2; ++kc) {
        if (kc) __syncthreads();
#pragma unroll
        for (int it = 0; it < 4; ++it) {
            int idx = it * 256 + t;          // 0..1023
            int r = idx >> 3, s = idx & 7;
            int gr = rowBase + r;
            uint4 v = make_uint4(0, 0, 0, 0);
            if (gr < N) v = Ag[(size_t)gr * 16 + kc * 8 + s];
            A4[r * 8 + (s ^ (r & 7))] = v;
            W4[r * 8 + (s ^ (r & 7))] = Wg[r * 16 + kc * 8 + s];
        }
        __syncthreads();
#pragma unroll
        for (int kk = 0; kk < 2; ++kk) {
            int slot = kk * 4 + lg;
            bf16x8 af[2], bfr[8];
#pragma unroll
            for (int rt = 0; rt < 2; ++rt) {
                int r = w * 32 + rt * 16 + lr;
                af[rt] = *(const bf16x8*)&A4[r * 8 + (slot ^ (r & 7))];
            }
#pragma unroll
            for (int ct = 0; ct < 8; ++ct) {
                int r = ct * 16 + lr;
                bfr[ct] = *(const bf16x8*)&W4[r * 8 + (slot ^ (r & 7))];
            }
#pragma unroll
            for (int rt = 0; rt < 2; ++rt)
#pragma unroll
                for (int ct = 0; ct < 8; ++ct)
                    acc[rt][ct] = __builtin_amdgcn_mfma_f32_16x16x32_bf16(
                        af[rt], bfr[ct], acc[rt][ct], 0, 0, 0);
        }
    }

    float cv[8];
    if (ADD_DEGC) {
#pragma unroll
        for (int ct = 0; ct < 8; ++ct) cv[ct] = cvec[ct * 16 + lr];
    }
    // C/D layout: reg j -> row = lg*4 + j (within 16), col = lr
#pragma unroll
    for (int rt = 0; rt < 2; ++rt) {
#pragma unroll
        for (int j = 0; j < 4; ++j) {
            int gr = rowBase + w * 32 + rt * 16 + lg * 4 + j;
            if (gr < N) {
                float d = ADD_DEGC ? (float)deg[gr] : 0.f;
#pragma unroll
                for (int ct = 0; ct < 8; ++ct) {
                    int gc = ct * 16 + lr;
                    float v = acc[rt][ct][j];
                    if (ADD_DEGC) v += d * cv[ct];
                    if (RELU) v = fmaxf(v, 0.f);
                    if (OUT_BF16) ((ushort*)Cout)[(size_t)gr * H + gc] = f2bf(v);
                    else ((float*)Cout)[(size_t)gr * H + gc] = v;
                }
            }
        }
    }
}

// ---------------- aggregation: dst[n] = relu(bias[n] + sum_{e in row n} p[cols[e]]) ----
// p is bf16 [N][128]; one wave per node; lane owns cols 2l,2l+1 (one uint = 2 bf16).

template<int OUT_BF16>
__global__ void aggregate_relu2(const float* __restrict__ bias, const ushort* __restrict__ p,
                                const int* __restrict__ off, const int* __restrict__ cols,
                                void* __restrict__ dst, int N)
{
    int node = blockIdx.x * 4 + (threadIdx.x >> 6);
    if (node >= N) return;
    int l = threadIdx.x & 63;
    int s = off[node], e = off[node + 1];
    const uint* pu = (const uint*)p;     // [N][64]
    float ax = 0.f, ay = 0.f;
    int i = s;
    for (; i + 4 <= e; i += 4) {
        int c0 = cols[i], c1 = cols[i + 1], c2 = cols[i + 2], c3 = cols[i + 3];
        uint v0 = pu[(size_t)c0 * 64 + l];
        uint v1 = pu[(size_t)c1 * 64 + l];
        uint v2 = pu[(size_t)c2 * 64 + l];
        uint v3 = pu[(size_t)c3 * 64 + l];
        ax += bf_lo(v0) + bf_lo(v1) + bf_lo(v2) + bf_lo(v3);
        ay += bf_hi(v0) + bf_hi(v1) + bf_hi(v2) + bf_hi(v3);
    }
    for (; i < e; ++i) {
        uint v = pu[(size_t)cols[i] * 64 + l];
        ax += bf_lo(v);
        ay += bf_hi(v);
    }
    float2 b = ((const float2*)bias)[(size_t)node * 64 + l];
    float ox = fmaxf(b.x + ax, 0.f);
    float oy = fmaxf(b.y + ay, 0.f);
    if (OUT_BF16) {
        ((uint*)dst)[(size_t)node * 64 + l] = (uint)f2bf(ox) | ((uint)f2bf(oy) << 16);
    } else {
        ((float2*)dst)[(size_t)node * 64 + l] = make_float2(ox, oy);
    }
}

// ---------------- launch ----------------

extern "C" void kernel_launch(void* const* d_in, const int* in_sizes, int n_in,
                              void* d_out, int out_size, void* d_ws, size_t ws_size,
                              hipStream_t stream)
{
    const float* x  = (const float*)d_in[0];
    const int*   ei = (const int*)d_in[1];
    const float* W1 = (const float*)d_in[2];
    const float* W2 = (const float*)d_in[3];
    const float* W3 = (const float*)d_in[4];
    const float* W4 = (const float*)d_in[5];
    int N   = in_sizes[0] / H;
    int E   = in_sizes[1] / 2;
    int HOP = in_sizes[2] / (H * H);

    char* ws = (char*)d_ws;
    int*   deg   = (int*)ws;                 // N
    int*   off   = deg + N;                  // N+1
    int*   cnt2  = off + N + 1;              // N
    int*   colss = cnt2 + N;                 // E
    int*   bsum  = colss + E;                // <=1024
    float* cvec  = (float*)(bsum + 1024);    // HOP*H
    size_t fo = (((size_t)((char*)(cvec + HOP * H) - ws)) + 255) & ~(size_t)255;
    ushort* xb  = (ushort*)(ws + fo);                    // N*H bf16
    ushort* W1b = xb + (size_t)N * H;                    // HOP*H*H bf16
    ushort* W2b = W1b + (size_t)HOP * H * H;             // HOP*H*H bf16
    ushort* p   = W2b + (size_t)HOP * H * H;             // N*H bf16
    ushort* h   = p + (size_t)N * H;                     // N*H bf16
    size_t fo2 = (((size_t)((char*)(h + (size_t)N * H) - ws)) + 255) & ~(size_t)255;
    float* bias = (float*)(ws + fo2);                    // N*H f32

    hipMemsetAsync(deg, 0, sizeof(int) * N, stream);
    hipMemsetAsync(cnt2, 0, sizeof(int) * N, stream);
    hist_kernel<<<(E + 255) / 256, 256, 0, stream>>>(ei, E, deg);

    int Bq = (N + 511) / 512;
    scan_reduce<<<Bq, 256, 0, stream>>>(deg, bsum, N);
    scan_bsums<<<1, 1024, 0, stream>>>(bsum, off, Bq, N);
    scan_write<<<Bq, 256, 0, stream>>>(deg, bsum, off, N);

    fill_kernel<<<(E + 255) / 256, 256, 0, stream>>>(ei, E, off, cnt2, colss);
    cvec_kernel<<<HOP, H, 0, stream>>>(W3, W4, cvec);

    // casts
    int nx8 = N * H / 8;
    cast_bf16<<<(nx8 + 255) / 256, 256, 0, stream>>>(x, xb, nx8);
    int nw8 = HOP * H * H / 8;
    cast_bf16<<<(nw8 + 255) / 256, 256, 0, stream>>>(W1, W1b, nw8);
    cast_bf16<<<(nw8 + 255) / 256, 256, 0, stream>>>(W2, W2b, nw8);

    int gblocks = (N + 127) / 128;
    float* out = (float*)d_out;

    // hop 0: h0 = relu(xb@W1[0]^T + deg*c0)
    if (HOP == 1) {
        gemm_mfma<1, 1, 0><<<gblocks, 256, 0, stream>>>(xb, W1b, deg, cvec, out, N);
        return;
    }
    gemm_mfma<1, 1, 1><<<gblocks, 256, 0, stream>>>(xb, W1b, deg, cvec, h, N);

    for (int i = 1; i < HOP; ++i) {
        int last = (i == HOP - 1);
        // p = h @ W2[i]^T  (bf16 out)
        gemm_mfma<0, 0, 1><<<gblocks, 256, 0, stream>>>(h, W2b + (size_t)i * H * H,
                                                        nullptr, nullptr, p, N);
        // bias = xb @ W1[i]^T + deg*c_i  (f32, no relu)
        gemm_mfma<1, 0, 0><<<gblocks, 256, 0, stream>>>(xb, W1b + (size_t)i * H * H,
                                                        deg, cvec + i * H, bias, N);
        // dst = relu(bias + A p)
        if (last)
            aggregate_relu2<0><<<(N + 3) / 4, 256, 0, stream>>>(bias, p, off, colss, out, N);
        else
            aggregate_relu2<1><<<(N + 3) / 4, 256, 0, stream>>>(bias, p, off, colss, h, N);
    }
}